// Round 1
// baseline (419.721 us; speedup 1.0000x reference)
//
#include <hip/hip_runtime.h>

namespace {
constexpr int Bn = 16, Hn = 512, Wn = 512;
constexpr int HW  = Hn * Wn;        // 262144
constexpr int CHW = 8 * HW;         // 2097152
constexpr int NCOL = Bn * Wn;       // 8192 dice columns
constexpr int WALK = 2;             // rows walked per wave
constexpr int GX   = Hn / (2 * WALK); // 128 (block = 2 rowgroups x WALK rows)
constexpr int NBLK = GX * Bn;       // 2048 blocks
constexpr int SLABN = NBLK * 512;   // 1,048,576 floats per partial table
constexpr int FBLK  = 32;           // fallback finisher blocks
constexpr int FBLK2 = 256;          // slab finisher blocks (8 bscal slots each)

constexpr float L2E  = 1.4426950408889634f;   // log2(e)
constexpr float LN2  = 0.6931471805599453f;
constexpr float CLMP = -144.26950408889634f;  // -100 / ln2 (clamp in log2 units)

__device__ __forceinline__ float frcp(float x) { return __builtin_amdgcn_rcpf(x); }
#if __has_builtin(__builtin_amdgcn_exp2f)
__device__ __forceinline__ float fexp2(float x) { return __builtin_amdgcn_exp2f(x); }
#else
__device__ __forceinline__ float fexp2(float x) { return exp2f(x); }
#endif
#if __has_builtin(__builtin_amdgcn_logf)
__device__ __forceinline__ float flog2(float x) { return __builtin_amdgcn_logf(x); }
#else
__device__ __forceinline__ float flog2(float x) { return log2f(x); }
#endif
} // namespace

// n[c](h,w) = sigmoid(c_map[c][h+DY[c]][w+DX[c]]), zero outside image.
// vote[i] = p[i] * n[7-i].  DX = {1,0,-1,1,-1,1,0,-1}, DY = {1,1,1,0,0,-1,-1,-1}.
// All BCE sums accumulated in log2 units via log-of-product fusion; one x ln2
// conversion at the bscal write restores natural-log units.
//
// R1 experiment: (a) __launch_bounds__(256,8) -> VGPR<=64 so all 2048 blocks
// (8/CU) are co-resident in ONE round (was 7/CU + straggler round at ~12% occ);
// (b) SLAB=true replaces the 3.1M contended end-of-block fp32 atomics with
// direct per-block partial stores (same 12.6 MB write bytes, no contention,
// no serialized drain tail); finisher reduces the slabs.

template <bool SLAB>
__global__ __launch_bounds__(256, 8) void bicon_main(
    const float* __restrict__ c_map,
    const int*   __restrict__ target,
    const int*   __restrict__ con_target,
    float* __restrict__ col_i, float* __restrict__ col_j, float* __restrict__ col_x,
    double* __restrict__ bscal)
{
    const int tid  = threadIdx.x;        // 0..255
    const int lane = tid & 63;
    const int wv   = tid >> 6;           // 0..3
    const int half = wv & 1;             // 256-col half
    const int rg   = wv >> 1;            // row-group within block
    const int b    = blockIdx.y;
    const int hstart = blockIdx.x * (2 * WALK) + rg * WALK;
    const int wq   = half * 256 + lane * 4;   // first of this lane's 4 columns

    const float* cm = c_map      + (size_t)b * CHW;
    const int*   ct = con_target + (size_t)b * CHW;
    const int*   tg = target     + (size_t)b * HW;

    float s_con = 0.f, s_bi = 0.f, s_bce = 0.f, s_dec = 0.f;   // log2 units
    float ci[4] = {0, 0, 0, 0}, cj[4] = {0, 0, 0, 0}, cx[4] = {0, 0, 0, 0};

    auto sig4 = [&](const float4& v, float s[4]) {
        s[0] = frcp(1.f + fexp2(-v.x * L2E));
        s[1] = frcp(1.f + fexp2(-v.y * L2E));
        s[2] = frcp(1.f + fexp2(-v.z * L2E));
        s[3] = frcp(1.f + fexp2(-v.w * L2E));
    };

    // ---- carried window: sigma(ch0..2)@h, sigma(ch5..7)@h-1 ----
    float C0[4], C1[4], C2[4], P5[4], P6[4], P7[4];
    {
        const int pb = hstart * Wn + wq;
        sig4(*(const float4*)(cm + 0 * HW + pb), C0);
        sig4(*(const float4*)(cm + 1 * HW + pb), C1);
        sig4(*(const float4*)(cm + 2 * HW + pb), C2);
    }
    if (hstart > 0) {   // wave-uniform
        const int pb = (hstart - 1) * Wn + wq;
        sig4(*(const float4*)(cm + 5 * HW + pb), P5);
        sig4(*(const float4*)(cm + 6 * HW + pb), P6);
        sig4(*(const float4*)(cm + 7 * HW + pb), P7);
    } else {
#pragma unroll
        for (int k = 0; k < 4; ++k) { P5[k] = 0.f; P6[k] = 0.f; P7[k] = 0.f; }
    }

    const bool edR = (wq + 4 == Wn);
    const bool edL = (wq == 0);

    int h = hstart;
#pragma unroll 1
    for (int r = 0; r < WALK; ++r, ++h) {
        const int  base  = h * Wn + wq;
        const bool hasDn = (h + 1 < Hn);
        const bool hasUp = (h > 0);

        // ---- independent loads first ----
        const float4 xa3 = *(const float4*)(cm + 3 * HW + base);
        const float4 xa4 = *(const float4*)(cm + 4 * HW + base);
        const float4 xa5 = *(const float4*)(cm + 5 * HW + base);
        const float4 xa6 = *(const float4*)(cm + 6 * HW + base);
        const float4 xa7 = *(const float4*)(cm + 7 * HW + base);
        const float4 xf0 = *(const float4*)(cm + 0 * HW + base + Wn);
        const float4 xf1 = *(const float4*)(cm + 1 * HW + base + Wn);
        const float4 xf2 = *(const float4*)(cm + 2 * HW + base + Wn);
        const float bx0 = cm[0 * HW + base + Wn + 4];
        const float bx2 = cm[2 * HW + base + Wn - 1];
        const float bx3 = cm[3 * HW + base + 4];
        const float bx4 = cm[4 * HW + base - 1];
        const float bx5 = cm[5 * HW + base - Wn + 4];
        const float bx7 = cm[7 * HW + base - Wn - 1];
        const int4  t4  = *(const int4*)(tg + base);

        unsigned lo = 0u;
#pragma unroll
        for (int c = 0; c < 8; ++c) {
            const int4 u = *(const int4*)(ct + c * HW + base);
            lo |= ((unsigned)u.x << c)        | ((unsigned)u.y << (8 + c)) |
                  ((unsigned)u.z << (16 + c)) | ((unsigned)u.w << (24 + c));
        }

        // ---- fresh centers ch3-7: sigma + conmap d-product accumulation ----
        float dp[4] = {1.f, 1.f, 1.f, 1.f};   // prod of d over ch3..7
        float ys[4] = {0.f, 0.f, 0.f, 0.f};   // sum of y where bit==0
        float c3[4], c4[4], c5[4], c6[4], c7[4];
        auto fresh = [&](int c, const float4& v, float s[4]) {
            const float xs[4] = {v.x, v.y, v.z, v.w};
#pragma unroll
            for (int k = 0; k < 4; ++k) {
                const float y = xs[k] * L2E;
                const float e = fexp2(-y);
                const float d = 1.f + e;
                s[k] = frcp(d);
                dp[k] *= d;
                ys[k] += ((lo >> (8 * k + c)) & 1u) ? 0.f : y;
            }
        };
        fresh(3, xa3, c3); fresh(4, xa4, c4); fresh(5, xa5, c5);
        fresh(6, xa6, c6); fresh(7, xa7, c7);

        // ---- conmap: carried ch0-2 select-product + ch3-7 d-form (2 logs/px) --
#pragma unroll
        for (int k = 0; k < 4; ++k) {
            const float q0 = ((lo >> (8 * k + 0)) & 1u) ? C0[k] : 1.f - C0[k];
            const float q1 = ((lo >> (8 * k + 1)) & 1u) ? C1[k] : 1.f - C1[k];
            const float q2 = ((lo >> (8 * k + 2)) & 1u) ? C2[k] : 1.f - C2[k];
            s_con += flog2(q0 * q1 * q2) - flog2(dp[k]) - ys[k];
        }

        // ---- next-row sigmas + boundary sigmas ----
        float F0[4], F1[4], F2[4];
        sig4(xf0, F0); sig4(xf1, F1); sig4(xf2, F2);
        const float s0b = frcp(1.f + fexp2(-bx0 * L2E));
        const float s2b = frcp(1.f + fexp2(-bx2 * L2E));
        const float s3b = frcp(1.f + fexp2(-bx3 * L2E));
        const float s4b = frcp(1.f + fexp2(-bx4 * L2E));
        const float s5b = frcp(1.f + fexp2(-bx5 * L2E));
        const float s7b = frcp(1.f + fexp2(-bx7 * L2E));

        // ---- neighbor arrays n[c] (masked shifts) ----
        float n0[4], n1[4], n2[4], n3[4], n4[4], n5[4], n6[4], n7[4];
#pragma unroll
        for (int k = 0; k < 3; ++k) {
            n0[k] = F0[k + 1]; n3[k] = c3[k + 1]; n5[k] = P5[k + 1];
            n2[k + 1] = F2[k]; n4[k + 1] = c4[k]; n7[k + 1] = P7[k];
        }
        n0[3] = edR ? 0.f : s0b;  n3[3] = edR ? 0.f : s3b;  n5[3] = edR ? 0.f : s5b;
        n2[0] = edL ? 0.f : s2b;  n4[0] = edL ? 0.f : s4b;  n7[0] = edL ? 0.f : s7b;
#pragma unroll
        for (int k = 0; k < 4; ++k) {
            n1[k] = hasDn ? F1[k] : 0.f;
            n6[k] = hasUp ? P6[k] : 0.f;
            if (!hasDn) { n0[k] = 0.f; n2[k] = 0.f; }
            if (!hasUp) { n5[k] = 0.f; n7[k] = 0.f; }
        }

        // ---- votes + bimap product accumulation ----
        float vmax[4] = {0.f, 0.f, 0.f, 0.f}, vmin[4] = {2.f, 2.f, 2.f, 2.f};
        float pr[4]   = {1.f, 1.f, 1.f, 1.f};
        float zc[4]   = {0.f, 0.f, 0.f, 0.f};   // count of bit=1 zero-votes
        auto vote = [&](int i, const float p[4], const float n[4]) {
#pragma unroll
            for (int k = 0; k < 4; ++k) {
                const float v = p[k] * n[k];
                vmax[k] = fmaxf(vmax[k], v);
                vmin[k] = fminf(vmin[k], v);
                const bool bit = (lo >> (8 * k + i)) & 1u;
                const bool z   = bit && (v == 0.f);     // only from masked edges
                float sel = bit ? v : 1.f - v;
                sel = z ? 1.f : sel;
                zc[k] += z ? 1.f : 0.f;
                pr[k] *= sel;
            }
        };
        vote(0, C0, n7); vote(1, C1, n6); vote(2, C2, n5); vote(3, c3, n4);
#pragma unroll
        for (int k = 0; k < 4; ++k) { s_bi += flog2(pr[k]); pr[k] = 1.f; }
        vote(4, c4, n3); vote(5, c5, n2); vote(6, c6, n1); vote(7, c7, n0);
#pragma unroll
        for (int k = 0; k < 4; ++k) { s_bi += flog2(pr[k]) + CLMP * zc[k]; }

        // ---- per-pixel tail ----
        const int tk[4] = {t4.x, t4.y, t4.z, t4.w};
#pragma unroll
        for (int k = 0; k < 4; ++k) {
            const float fm = vmax[k];
            s_bce += fmaxf(flog2(tk[k] ? fm : 1.f - fm), CLMP);
            const int sc = __popc((int)((lo >> (8 * k)) & 0xffu));
            s_dec += (sc > 0 && sc < 8) ? fmaxf(flog2(1.f - vmin[k]), CLMP) : 0.f;
            ci[k] += (float)tk[k];
            cj[k] += fm;
            cx[k] += tk[k] ? fm : 0.f;
        }

        // ---- rotate window ----
#pragma unroll
        for (int k = 0; k < 4; ++k) {
            C0[k] = F0[k]; C1[k] = F1[k]; C2[k] = F2[k];
            P5[k] = c5[k]; P6[k] = c6[k]; P7[k] = c7[k];
        }
    }

    // ---- dice partials -> LDS ----
    __shared__ float cred[3][4][256];   // 12 KB
#pragma unroll
    for (int k = 0; k < 4; ++k) {
        cred[0][wv][(lane << 2) + k] = ci[k];
        cred[1][wv][(lane << 2) + k] = cj[k];
        cred[2][wv][(lane << 2) + k] = cx[k];
    }

    // ---- scalar sums: wave shuffle reduction ----
#pragma unroll
    for (int off = 32; off > 0; off >>= 1) {
        s_con += __shfl_down(s_con, off);
        s_bi  += __shfl_down(s_bi,  off);
        s_bce += __shfl_down(s_bce, off);
        s_dec += __shfl_down(s_dec, off);
    }
    __shared__ float wred[4][4];
    if (lane == 0) {   // convert log2 -> ln units here (one mul per sum)
        wred[wv][0] = s_con * LN2; wred[wv][1] = s_bi * LN2;
        wred[wv][2] = s_bce * LN2; wred[wv][3] = s_dec * LN2;
    }
    __syncthreads();

    if constexpr (SLAB) {
        // direct per-block partial store: zero contention, coalesced dwords
        const size_t sb = ((size_t)(b * GX + blockIdx.x)) << 9;
#pragma unroll
        for (int j = tid; j < 512; j += 256) {
            const int hj = j >> 8, cidx = j & 255;
            col_i[sb + j] = cred[0][hj][cidx] + cred[0][hj + 2][cidx];
            col_j[sb + j] = cred[1][hj][cidx] + cred[1][hj + 2][cidx];
            col_x[sb + j] = cred[2][hj][cidx] + cred[2][hj + 2][cidx];
        }
    } else {
        // fallback: contended atomics into 8192-entry col tables
#pragma unroll
        for (int j = tid; j < 512; j += 256) {
            const int hj = j >> 8, cidx = j & 255;
            atomicAdd(&col_i[b * Wn + j], cred[0][hj][cidx] + cred[0][hj + 2][cidx]);
            atomicAdd(&col_j[b * Wn + j], cred[1][hj][cidx] + cred[1][hj + 2][cidx]);
            atomicAdd(&col_x[b * Wn + j], cred[2][hj][cidx] + cred[2][hj + 2][cidx]);
        }
    }
    if (tid < 4) {
        bscal[((size_t)blockIdx.y * GX + blockIdx.x) * 4 + tid] =
            (double)(wred[0][tid] + wred[1][tid] + wred[2][tid] + wred[3][tid]);
    }
}

// Slab finisher: 256 blocks x 256 threads. Block bx owns 32 columns; each
// column's 128 gx-partials are summed by 8 threads (16 each) -> LDS -> lane.
__global__ __launch_bounds__(256) void bicon_finish_slab(
    const float* __restrict__ pI,
    const float* __restrict__ pJ,
    const float* __restrict__ pX,
    const double* __restrict__ bscal,
    float* __restrict__ out)
{
    const int tid = threadIdx.x;
    const int w32 = tid & 31;                 // which of the block's 32 columns
    const int p   = tid >> 5;                 // gx partition 0..7 (16 gx each)
    const int col = blockIdx.x * 32 + w32;    // 0..8191
    const int b   = col >> 9;
    const int w   = col & 511;

    float fi = 0.f, fj = 0.f, fx = 0.f;
    const size_t base = (((size_t)(b * GX + p * 16)) << 9) + w;
#pragma unroll
    for (int g = 0; g < 16; ++g) {
        const size_t idx = base + ((size_t)g << 9);
        fi += pI[idx]; fj += pJ[idx]; fx += pX[idx];
    }
    __shared__ float red[3][8][32];           // 3 KB
    red[0][p][w32] = fi; red[1][p][w32] = fj; red[2][p][w32] = fx;
    __syncthreads();

    double part = 0.0;
    if (tid < 32) {                           // dice term for 32 columns
        float si = 0.f, sj = 0.f, sx = 0.f;
#pragma unroll
        for (int q = 0; q < 8; ++q) {
            si += red[0][q][tid]; sj += red[1][q][tid]; sx += red[2][q][tid];
        }
        part = (1.0 - (2.0 * (double)sx + 0.001) /
                      ((double)si + (double)sj + 0.001)) / 8192.0;
    }
    if (tid >= 64 && tid < 72) {              // 8 bscal slots, on wave 1
        const int s = blockIdx.x * 8 + (tid - 64);
        const double c0 = bscal[s * 4 + 0], c1 = bscal[s * 4 + 1];
        const double c2 = bscal[s * 4 + 2], c3 = bscal[s * 4 + 3];
        part += -0.8 * c0 / 33554432.0 - 0.2 * c1 / 33554432.0
                - c2 / 4194304.0 - c3 / 4194304.0;
    }
#pragma unroll
    for (int off = 32; off > 0; off >>= 1) part += __shfl_down(part, off);
    __shared__ double red2[4];
    if ((tid & 63) == 0) red2[tid >> 6] = part;
    __syncthreads();
    if (tid == 0) atomicAdd(out, (float)(red2[0] + red2[1] + red2[2] + red2[3]));
}

// Fallback finisher (atomic path): cols already reduced, 32 blocks suffice.
__global__ __launch_bounds__(256) void bicon_finish(
    const float* __restrict__ col_i,
    const float* __restrict__ col_j,
    const float* __restrict__ col_x,
    const double* __restrict__ bscal,
    float* __restrict__ out)
{
    const int tid = threadIdx.x;
    const int col = blockIdx.x * 256 + tid;      // exactly NCOL threads total

    double part;
    {
        const float fi = col_i[col], fj = col_j[col], fx = col_x[col];
        part = (1.0 - (2.0 * (double)fx + 0.001) /
                      ((double)fi + (double)fj + 0.001)) / 8192.0;
    }
    if (tid < 64) {   // 64 bscal slots per block: 32 blocks * 64 = 2048 = NBLK
        const int s = blockIdx.x * 64 + tid;
        const double c0 = bscal[s * 4 + 0], c1 = bscal[s * 4 + 1];
        const double c2 = bscal[s * 4 + 2], c3 = bscal[s * 4 + 3];
        part += -0.8 * c0 / 33554432.0 - 0.2 * c1 / 33554432.0
                - c2 / 4194304.0 - c3 / 4194304.0;
    }
#pragma unroll
    for (int off = 32; off > 0; off >>= 1) part += __shfl_down(part, off);
    __shared__ double red[4];
    if ((tid & 63) == 0) red[tid >> 6] = part;
    __syncthreads();
    if (tid == 0) atomicAdd(out, (float)(red[0] + red[1] + red[2] + red[3]));
}

extern "C" void kernel_launch(void* const* d_in, const int* in_sizes, int n_in,
                              void* d_out, int out_size, void* d_ws, size_t ws_size,
                              hipStream_t stream) {
    const float* c_map      = (const float*)d_in[0];
    const int*   target     = (const int*)d_in[1];
    const int*   con_target = (const int*)d_in[2];
    float* out = (float*)d_out;

    char* ws = (char*)d_ws;
    const size_t slab_need = (size_t)3 * SLABN * sizeof(float)
                           + (size_t)NBLK * 4 * sizeof(double);   // ~12.65 MB

    dim3 grid(GX, Bn);       // 128 x 16 = 2048 blocks = 8/CU, fully resident
    dim3 block(256);

    hipMemsetAsync(d_out, 0, sizeof(float), stream);  // finisher atomics here

    if (ws_size >= slab_need) {
        float*  pI    = (float*)ws;                   // 2048 x 512 partials
        float*  pJ    = pI + SLABN;
        float*  pX    = pJ + SLABN;
        double* bscal = (double*)(ws + (size_t)3 * SLABN * sizeof(float));
        // no col memset needed: slabs are fully written
        bicon_main<true><<<grid, block, 0, stream>>>(c_map, target, con_target,
                                                     pI, pJ, pX, bscal);
        bicon_finish_slab<<<FBLK2, 256, 0, stream>>>(pI, pJ, pX, bscal, out);
    } else {
        float*  col_i = (float*)ws;                               // 8192 floats
        float*  col_j = col_i + NCOL;
        float*  col_x = col_j + NCOL;
        double* bscal = (double*)(ws + 3 * NCOL * sizeof(float)); // 2048*4 doubles
        hipMemsetAsync(d_ws, 0, 3 * NCOL * sizeof(float), stream);
        bicon_main<false><<<grid, block, 0, stream>>>(c_map, target, con_target,
                                                      col_i, col_j, col_x, bscal);
        bicon_finish<<<FBLK, 256, 0, stream>>>(col_i, col_j, col_x, bscal, out);
    }
}

// Round 2
// 302.407 us; speedup vs baseline: 1.3879x; 1.3879x over previous
//
#include <hip/hip_runtime.h>

namespace {
constexpr int Bn = 16, Hn = 512, Wn = 512;
constexpr int HW  = Hn * Wn;        // 262144
constexpr int CHW = 8 * HW;         // 2097152
constexpr int NCOL = Bn * Wn;       // 8192 dice columns
constexpr int WALK = 4;             // rows walked per thread (block covers WALK rows x 512 cols)
constexpr int GX   = Hn / WALK;     // 128
constexpr int NBLK = GX * Bn;       // 2048 blocks
constexpr int SLABN = NBLK * 512;   // 1,048,576 floats per partial table
constexpr int FBLK  = 32;           // fallback finisher blocks
constexpr int FBLK2 = 256;          // slab finisher blocks (8 bscal slots each)

constexpr float L2E  = 1.4426950408889634f;   // log2(e)
constexpr float LN2  = 0.6931471805599453f;
constexpr float CLMP = -144.26950408889634f;  // -100 / ln2 (clamp in log2 units)

__device__ __forceinline__ float frcp(float x) { return __builtin_amdgcn_rcpf(x); }
#if __has_builtin(__builtin_amdgcn_exp2f)
__device__ __forceinline__ float fexp2(float x) { return __builtin_amdgcn_exp2f(x); }
#else
__device__ __forceinline__ float fexp2(float x) { return exp2f(x); }
#endif
#if __has_builtin(__builtin_amdgcn_logf)
__device__ __forceinline__ float flog2(float x) { return __builtin_amdgcn_logf(x); }
#else
__device__ __forceinline__ float flog2(float x) { return log2f(x); }
#endif
} // namespace

// n[c](h,w) = sigmoid(c_map[c][h+DY[c]][w+DX[c]]), zero outside image.
// vote[i] = p[i] * n[7-i].  DX = {1,0,-1,1,-1,1,0,-1}, DY = {1,1,1,0,0,-1,-1,-1}.
// All BCE sums accumulated in log2 units via log-of-product fusion; one x ln2
// conversion at the bscal write restores natural-log units.
//
// R2: occupancy via genuine register reduction. R1 proved residency doubles
// when VGPR<=64 (Occ 28->73%) but launch_bounds-forcing spilled (456 MB
// scratch writes, VGPR=32). Here: 2 cols/thread x 4 rows instead of
// 4 cols x 2 rows -- all per-thread [4] arrays become [2], loads become
// float2/int2, per-thread px count unchanged. No forced bounds. Dice columns
// are now thread-exclusive -> LDS cred buffer deleted, direct float2 slab
// stores. Target: VGPR ~50 -> 8 blocks/CU in one grid round.

template <bool SLAB>
__global__ __launch_bounds__(256) void bicon_main(
    const float* __restrict__ c_map,
    const int*   __restrict__ target,
    const int*   __restrict__ con_target,
    float* __restrict__ col_i, float* __restrict__ col_j, float* __restrict__ col_x,
    double* __restrict__ bscal)
{
    const int tid  = threadIdx.x;        // 0..255
    const int lane = tid & 63;
    const int wv   = tid >> 6;           // 0..3 = column quarter
    const int b    = blockIdx.y;
    const int hstart = blockIdx.x * WALK;
    const int wq   = wv * 128 + lane * 2;   // first of this lane's 2 columns

    const float* cm = c_map      + (size_t)b * CHW;
    const int*   ct = con_target + (size_t)b * CHW;
    const int*   tg = target     + (size_t)b * HW;

    float s_con = 0.f, s_bi = 0.f, s_bce = 0.f, s_dec = 0.f;   // log2 units
    float ci[2] = {0, 0}, cj[2] = {0, 0}, cx[2] = {0, 0};

    auto sig2 = [&](const float2& v, float s[2]) {
        s[0] = frcp(1.f + fexp2(-v.x * L2E));
        s[1] = frcp(1.f + fexp2(-v.y * L2E));
    };

    // ---- carried window: sigma(ch0..2)@h, sigma(ch5..7)@h-1 ----
    float C0[2], C1[2], C2[2], P5[2], P6[2], P7[2];
    {
        const int pb = hstart * Wn + wq;
        sig2(*(const float2*)(cm + 0 * HW + pb), C0);
        sig2(*(const float2*)(cm + 1 * HW + pb), C1);
        sig2(*(const float2*)(cm + 2 * HW + pb), C2);
    }
    if (hstart > 0) {   // block-uniform
        const int pb = (hstart - 1) * Wn + wq;
        sig2(*(const float2*)(cm + 5 * HW + pb), P5);
        sig2(*(const float2*)(cm + 6 * HW + pb), P6);
        sig2(*(const float2*)(cm + 7 * HW + pb), P7);
    } else {
#pragma unroll
        for (int k = 0; k < 2; ++k) { P5[k] = 0.f; P6[k] = 0.f; P7[k] = 0.f; }
    }

    const bool edR = (wq + 2 == Wn);
    const bool edL = (wq == 0);

    int h = hstart;
#pragma unroll 1
    for (int r = 0; r < WALK; ++r, ++h) {
        const int  base  = h * Wn + wq;
        const bool hasDn = (h + 1 < Hn);
        const bool hasUp = (h > 0);

        // ---- independent loads first ----
        const float2 xa3 = *(const float2*)(cm + 3 * HW + base);
        const float2 xa4 = *(const float2*)(cm + 4 * HW + base);
        const float2 xa5 = *(const float2*)(cm + 5 * HW + base);
        const float2 xa6 = *(const float2*)(cm + 6 * HW + base);
        const float2 xa7 = *(const float2*)(cm + 7 * HW + base);
        const float2 xf0 = *(const float2*)(cm + 0 * HW + base + Wn);
        const float2 xf1 = *(const float2*)(cm + 1 * HW + base + Wn);
        const float2 xf2 = *(const float2*)(cm + 2 * HW + base + Wn);
        const float bx0 = cm[0 * HW + base + Wn + 2];
        const float bx2 = cm[2 * HW + base + Wn - 1];
        const float bx3 = cm[3 * HW + base + 2];
        const float bx4 = cm[4 * HW + base - 1];
        const float bx5 = cm[5 * HW + base - Wn + 2];
        const float bx7 = cm[7 * HW + base - Wn - 1];
        const int2  t2  = *(const int2*)(tg + base);

        unsigned lo = 0u;
#pragma unroll
        for (int c = 0; c < 8; ++c) {
            const int2 u = *(const int2*)(ct + c * HW + base);
            lo |= ((unsigned)u.x << c) | ((unsigned)u.y << (8 + c));
        }

        // ---- fresh centers ch3-7: sigma + conmap d-product accumulation ----
        float dp[2] = {1.f, 1.f};   // prod of d over ch3..7
        float ys[2] = {0.f, 0.f};   // sum of y where bit==0
        float c3[2], c4[2], c5[2], c6[2], c7[2];
        auto fresh = [&](int c, const float2& v, float s[2]) {
            const float xs[2] = {v.x, v.y};
#pragma unroll
            for (int k = 0; k < 2; ++k) {
                const float y = xs[k] * L2E;
                const float e = fexp2(-y);
                const float d = 1.f + e;
                s[k] = frcp(d);
                dp[k] *= d;
                ys[k] += ((lo >> (8 * k + c)) & 1u) ? 0.f : y;
            }
        };
        fresh(3, xa3, c3); fresh(4, xa4, c4); fresh(5, xa5, c5);
        fresh(6, xa6, c6); fresh(7, xa7, c7);

        // ---- conmap: carried ch0-2 select-product + ch3-7 d-form (2 logs/px) --
#pragma unroll
        for (int k = 0; k < 2; ++k) {
            const float q0 = ((lo >> (8 * k + 0)) & 1u) ? C0[k] : 1.f - C0[k];
            const float q1 = ((lo >> (8 * k + 1)) & 1u) ? C1[k] : 1.f - C1[k];
            const float q2 = ((lo >> (8 * k + 2)) & 1u) ? C2[k] : 1.f - C2[k];
            s_con += flog2(q0 * q1 * q2) - flog2(dp[k]) - ys[k];
        }

        // ---- next-row sigmas + boundary sigmas ----
        float F0[2], F1[2], F2[2];
        sig2(xf0, F0); sig2(xf1, F1); sig2(xf2, F2);
        const float s0b = frcp(1.f + fexp2(-bx0 * L2E));
        const float s2b = frcp(1.f + fexp2(-bx2 * L2E));
        const float s3b = frcp(1.f + fexp2(-bx3 * L2E));
        const float s4b = frcp(1.f + fexp2(-bx4 * L2E));
        const float s5b = frcp(1.f + fexp2(-bx5 * L2E));
        const float s7b = frcp(1.f + fexp2(-bx7 * L2E));

        // ---- neighbor arrays n[c] (masked shifts) ----
        float n0[2], n1[2], n2[2], n3[2], n4[2], n5[2], n6[2], n7[2];
        n0[0] = F0[1]; n3[0] = c3[1]; n5[0] = P5[1];
        n2[1] = F2[0]; n4[1] = c4[0]; n7[1] = P7[0];
        n0[1] = edR ? 0.f : s0b;  n3[1] = edR ? 0.f : s3b;  n5[1] = edR ? 0.f : s5b;
        n2[0] = edL ? 0.f : s2b;  n4[0] = edL ? 0.f : s4b;  n7[0] = edL ? 0.f : s7b;
#pragma unroll
        for (int k = 0; k < 2; ++k) {
            n1[k] = hasDn ? F1[k] : 0.f;
            n6[k] = hasUp ? P6[k] : 0.f;
            if (!hasDn) { n0[k] = 0.f; n2[k] = 0.f; }
            if (!hasUp) { n5[k] = 0.f; n7[k] = 0.f; }
        }

        // ---- votes + bimap product accumulation ----
        float vmax[2] = {0.f, 0.f}, vmin[2] = {2.f, 2.f};
        float pr[2]   = {1.f, 1.f};
        float zc[2]   = {0.f, 0.f};   // count of bit=1 zero-votes
        auto vote = [&](int i, const float p[2], const float n[2]) {
#pragma unroll
            for (int k = 0; k < 2; ++k) {
                const float v = p[k] * n[k];
                vmax[k] = fmaxf(vmax[k], v);
                vmin[k] = fminf(vmin[k], v);
                const bool bit = (lo >> (8 * k + i)) & 1u;
                const bool z   = bit && (v == 0.f);     // only from masked edges
                float sel = bit ? v : 1.f - v;
                sel = z ? 1.f : sel;
                zc[k] += z ? 1.f : 0.f;
                pr[k] *= sel;
            }
        };
        vote(0, C0, n7); vote(1, C1, n6); vote(2, C2, n5); vote(3, c3, n4);
#pragma unroll
        for (int k = 0; k < 2; ++k) { s_bi += flog2(pr[k]); pr[k] = 1.f; }
        vote(4, c4, n3); vote(5, c5, n2); vote(6, c6, n1); vote(7, c7, n0);
#pragma unroll
        for (int k = 0; k < 2; ++k) { s_bi += flog2(pr[k]) + CLMP * zc[k]; }

        // ---- per-pixel tail ----
        const int tk[2] = {t2.x, t2.y};
#pragma unroll
        for (int k = 0; k < 2; ++k) {
            const float fm = vmax[k];
            s_bce += fmaxf(flog2(tk[k] ? fm : 1.f - fm), CLMP);
            const int sc = __popc((int)((lo >> (8 * k)) & 0xffu));
            s_dec += (sc > 0 && sc < 8) ? fmaxf(flog2(1.f - vmin[k]), CLMP) : 0.f;
            ci[k] += (float)tk[k];
            cj[k] += fm;
            cx[k] += tk[k] ? fm : 0.f;
        }

        // ---- rotate window ----
#pragma unroll
        for (int k = 0; k < 2; ++k) {
            C0[k] = F0[k]; C1[k] = F1[k]; C2[k] = F2[k];
            P5[k] = c5[k]; P6[k] = c6[k]; P7[k] = c7[k];
        }
    }

    // ---- dice partials: thread-exclusive columns, direct store ----
    if constexpr (SLAB) {
        const size_t sb = ((size_t)(b * GX + blockIdx.x)) << 9;
        float2 vi; vi.x = ci[0]; vi.y = ci[1];
        float2 vj; vj.x = cj[0]; vj.y = cj[1];
        float2 vx; vx.x = cx[0]; vx.y = cx[1];
        *(float2*)(col_i + sb + wq) = vi;
        *(float2*)(col_j + sb + wq) = vj;
        *(float2*)(col_x + sb + wq) = vx;
    } else {
#pragma unroll
        for (int k = 0; k < 2; ++k) {
            atomicAdd(&col_i[b * Wn + wq + k], ci[k]);
            atomicAdd(&col_j[b * Wn + wq + k], cj[k]);
            atomicAdd(&col_x[b * Wn + wq + k], cx[k]);
        }
    }

    // ---- scalar sums: wave shuffle reduction ----
#pragma unroll
    for (int off = 32; off > 0; off >>= 1) {
        s_con += __shfl_down(s_con, off);
        s_bi  += __shfl_down(s_bi,  off);
        s_bce += __shfl_down(s_bce, off);
        s_dec += __shfl_down(s_dec, off);
    }
    __shared__ float wred[4][4];
    if (lane == 0) {   // convert log2 -> ln units here (one mul per sum)
        wred[wv][0] = s_con * LN2; wred[wv][1] = s_bi * LN2;
        wred[wv][2] = s_bce * LN2; wred[wv][3] = s_dec * LN2;
    }
    __syncthreads();
    if (tid < 4) {
        bscal[((size_t)b * GX + blockIdx.x) * 4 + tid] =
            (double)(wred[0][tid] + wred[1][tid] + wred[2][tid] + wred[3][tid]);
    }
}

// Slab finisher: 256 blocks x 256 threads. Block bx owns 32 columns; each
// column's 128 gx-partials are summed by 8 threads (16 each) -> LDS -> lane.
__global__ __launch_bounds__(256) void bicon_finish_slab(
    const float* __restrict__ pI,
    const float* __restrict__ pJ,
    const float* __restrict__ pX,
    const double* __restrict__ bscal,
    float* __restrict__ out)
{
    const int tid = threadIdx.x;
    const int w32 = tid & 31;                 // which of the block's 32 columns
    const int p   = tid >> 5;                 // gx partition 0..7 (16 gx each)
    const int col = blockIdx.x * 32 + w32;    // 0..8191
    const int b   = col >> 9;
    const int w   = col & 511;

    float fi = 0.f, fj = 0.f, fx = 0.f;
    const size_t base = (((size_t)(b * GX + p * 16)) << 9) + w;
#pragma unroll
    for (int g = 0; g < 16; ++g) {
        const size_t idx = base + ((size_t)g << 9);
        fi += pI[idx]; fj += pJ[idx]; fx += pX[idx];
    }
    __shared__ float red[3][8][32];           // 3 KB
    red[0][p][w32] = fi; red[1][p][w32] = fj; red[2][p][w32] = fx;
    __syncthreads();

    double part = 0.0;
    if (tid < 32) {                           // dice term for 32 columns
        float si = 0.f, sj = 0.f, sx = 0.f;
#pragma unroll
        for (int q = 0; q < 8; ++q) {
            si += red[0][q][tid]; sj += red[1][q][tid]; sx += red[2][q][tid];
        }
        part = (1.0 - (2.0 * (double)sx + 0.001) /
                      ((double)si + (double)sj + 0.001)) / 8192.0;
    }
    if (tid >= 64 && tid < 72) {              // 8 bscal slots, on wave 1
        const int s = blockIdx.x * 8 + (tid - 64);
        const double c0 = bscal[s * 4 + 0], c1 = bscal[s * 4 + 1];
        const double c2 = bscal[s * 4 + 2], c3 = bscal[s * 4 + 3];
        part += -0.8 * c0 / 33554432.0 - 0.2 * c1 / 33554432.0
                - c2 / 4194304.0 - c3 / 4194304.0;
    }
#pragma unroll
    for (int off = 32; off > 0; off >>= 1) part += __shfl_down(part, off);
    __shared__ double red2[4];
    if ((tid & 63) == 0) red2[tid >> 6] = part;
    __syncthreads();
    if (tid == 0) atomicAdd(out, (float)(red2[0] + red2[1] + red2[2] + red2[3]));
}

// Fallback finisher (atomic path): cols already reduced, 32 blocks suffice.
__global__ __launch_bounds__(256) void bicon_finish(
    const float* __restrict__ col_i,
    const float* __restrict__ col_j,
    const float* __restrict__ col_x,
    const double* __restrict__ bscal,
    float* __restrict__ out)
{
    const int tid = threadIdx.x;
    const int col = blockIdx.x * 256 + tid;      // exactly NCOL threads total

    double part;
    {
        const float fi = col_i[col], fj = col_j[col], fx = col_x[col];
        part = (1.0 - (2.0 * (double)fx + 0.001) /
                      ((double)fi + (double)fj + 0.001)) / 8192.0;
    }
    if (tid < 64) {   // 64 bscal slots per block: 32 blocks * 64 = 2048 = NBLK
        const int s = blockIdx.x * 64 + tid;
        const double c0 = bscal[s * 4 + 0], c1 = bscal[s * 4 + 1];
        const double c2 = bscal[s * 4 + 2], c3 = bscal[s * 4 + 3];
        part += -0.8 * c0 / 33554432.0 - 0.2 * c1 / 33554432.0
                - c2 / 4194304.0 - c3 / 4194304.0;
    }
#pragma unroll
    for (int off = 32; off > 0; off >>= 1) part += __shfl_down(part, off);
    __shared__ double red[4];
    if ((tid & 63) == 0) red[tid >> 6] = part;
    __syncthreads();
    if (tid == 0) atomicAdd(out, (float)(red[0] + red[1] + red[2] + red[3]));
}

extern "C" void kernel_launch(void* const* d_in, const int* in_sizes, int n_in,
                              void* d_out, int out_size, void* d_ws, size_t ws_size,
                              hipStream_t stream) {
    const float* c_map      = (const float*)d_in[0];
    const int*   target     = (const int*)d_in[1];
    const int*   con_target = (const int*)d_in[2];
    float* out = (float*)d_out;

    char* ws = (char*)d_ws;
    const size_t slab_need = (size_t)3 * SLABN * sizeof(float)
                           + (size_t)NBLK * 4 * sizeof(double);   // ~12.65 MB

    dim3 grid(GX, Bn);       // 128 x 16 = 2048 blocks
    dim3 block(256);

    hipMemsetAsync(d_out, 0, sizeof(float), stream);  // finisher atomics here

    if (ws_size >= slab_need) {
        float*  pI    = (float*)ws;                   // 2048 x 512 partials
        float*  pJ    = pI + SLABN;
        float*  pX    = pJ + SLABN;
        double* bscal = (double*)(ws + (size_t)3 * SLABN * sizeof(float));
        // no col memset needed: slabs are fully written
        bicon_main<true><<<grid, block, 0, stream>>>(c_map, target, con_target,
                                                     pI, pJ, pX, bscal);
        bicon_finish_slab<<<FBLK2, 256, 0, stream>>>(pI, pJ, pX, bscal, out);
    } else {
        float*  col_i = (float*)ws;                               // 8192 floats
        float*  col_j = col_i + NCOL;
        float*  col_x = col_j + NCOL;
        double* bscal = (double*)(ws + 3 * NCOL * sizeof(float)); // 2048*4 doubles
        hipMemsetAsync(d_ws, 0, 3 * NCOL * sizeof(float), stream);
        bicon_main<false><<<grid, block, 0, stream>>>(c_map, target, con_target,
                                                      col_i, col_j, col_x, bscal);
        bicon_finish<<<FBLK, 256, 0, stream>>>(col_i, col_j, col_x, bscal, out);
    }
}

// Round 3
// 299.458 us; speedup vs baseline: 1.4016x; 1.0098x over previous
//
#include <hip/hip_runtime.h>

namespace {
constexpr int Bn = 16, Hn = 512, Wn = 512;
constexpr int HW  = Hn * Wn;        // 262144
constexpr int CHW = 8 * HW;         // 2097152
constexpr int NCOL = Bn * Wn;       // 8192 dice columns
constexpr int WALK = 4;             // rows walked per thread
constexpr int GX   = Hn / WALK;     // 128
constexpr int NBLK = GX * Bn;       // 2048 blocks
constexpr int SLABN = NBLK * 512;   // 1,048,576 floats per partial table
constexpr int FBLK  = 32;           // fallback finisher blocks
constexpr int FBLK2 = 256;          // slab finisher blocks (8 bscal slots each)

constexpr float L2E  = 1.4426950408889634f;   // log2(e)
constexpr float LN2  = 0.6931471805599453f;
constexpr float CLMP = -144.26950408889634f;  // -100 / ln2 (clamp in log2 units)

__device__ __forceinline__ float frcp(float x) { return __builtin_amdgcn_rcpf(x); }
#if __has_builtin(__builtin_amdgcn_exp2f)
__device__ __forceinline__ float fexp2(float x) { return __builtin_amdgcn_exp2f(x); }
#else
__device__ __forceinline__ float fexp2(float x) { return exp2f(x); }
#endif
#if __has_builtin(__builtin_amdgcn_logf)
__device__ __forceinline__ float flog2(float x) { return __builtin_amdgcn_logf(x); }
#else
__device__ __forceinline__ float flog2(float x) { return log2f(x); }
#endif
} // namespace

// n[c](h,w) = sigmoid(c_map[c][h+DY[c]][w+DX[c]]), zero outside image.
// vote[i] = p[i] * n[7-i].  DX = {1,0,-1,1,-1,1,0,-1}, DY = {1,1,1,0,0,-1,-1,-1}.
// BCE sums in log2 units via log-of-product fusion; one x ln2 at bscal write.
//
// R3: software pipeline. R0 (occ 28%) == R2 (occ 55%) == 115us proved the
// stall is NOT occupancy/granularity: the rolled loop loads row h and uses
// it in the same iteration -> one full memory latency exposed per row-iter.
// Now: issue ALL row h+1 loads (one Row struct, ~8.5KB/wave) BEFORE computing
// row h; in-order vmcnt means row-h waits don't drain row-h+1 loads. Full
// unroll folds guards/rotation. Plus bijective XCD-chunk swizzle (T1) so
// adjacent-gx blocks (boundary-row re-reads) share an XCD L2.
// Tripwire: WRITE_SIZE must stay 12.35MB (spill detector, R1 lesson).

struct Row {
    float2 a3, a4, a5, a6, a7;   // row h, ch3-7
    float2 f0, f1, f2;           // row h+1, ch0-2
    float  b0, b2, b3, b4, b5, b7;  // boundary scalars for row h
    int2   t;                    // target row h
    int2   u0, u1, u2, u3, u4, u5, u6, u7;  // con_target row h
};

template <bool SLAB>
__global__ __launch_bounds__(256) void bicon_main(
    const float* __restrict__ c_map,
    const int*   __restrict__ target,
    const int*   __restrict__ con_target,
    float* __restrict__ col_i, float* __restrict__ col_j, float* __restrict__ col_x,
    double* __restrict__ bscal)
{
    const int tid  = threadIdx.x;        // 0..255
    const int lane = tid & 63;
    const int wv   = tid >> 6;           // 0..3 = column quarter

    // XCD-chunk swizzle: hw dispatch round-robins across 8 XCDs; remap so
    // each XCD owns 256 consecutive work ids (= 2 full b-rows of gx).
    const int hwid = blockIdx.y * GX + blockIdx.x;
    const int work = (hwid & 7) * (NBLK / 8) + (hwid >> 3);
    const int gx   = work & (GX - 1);
    const int b    = work >> 7;          // work / GX

    const int hstart = gx * WALK;
    const int wq   = wv * 128 + lane * 2;   // first of this lane's 2 columns

    const float* cm = c_map      + (size_t)b * CHW;
    const int*   ct = con_target + (size_t)b * CHW;
    const int*   tg = target     + (size_t)b * HW;

    float s_con = 0.f, s_bi = 0.f, s_bce = 0.f, s_dec = 0.f;   // log2 units
    float ci[2] = {0, 0}, cj[2] = {0, 0}, cx[2] = {0, 0};

    auto sig2 = [&](const float2& v, float s[2]) {
        s[0] = frcp(1.f + fexp2(-v.x * L2E));
        s[1] = frcp(1.f + fexp2(-v.y * L2E));
    };

    auto issue = [&](int hh, Row& R) {
        const int bs = hh * Wn + wq;
        R.a3 = *(const float2*)(cm + 3 * HW + bs);
        R.a4 = *(const float2*)(cm + 4 * HW + bs);
        R.a5 = *(const float2*)(cm + 5 * HW + bs);
        R.a6 = *(const float2*)(cm + 6 * HW + bs);
        R.a7 = *(const float2*)(cm + 7 * HW + bs);
        R.f0 = *(const float2*)(cm + 0 * HW + bs + Wn);
        R.f1 = *(const float2*)(cm + 1 * HW + bs + Wn);
        R.f2 = *(const float2*)(cm + 2 * HW + bs + Wn);
        R.b0 = cm[0 * HW + bs + Wn + 2];
        R.b2 = cm[2 * HW + bs + Wn - 1];
        R.b3 = cm[3 * HW + bs + 2];
        R.b4 = cm[4 * HW + bs - 1];
        R.b5 = cm[5 * HW + bs - Wn + 2];
        R.b7 = cm[7 * HW + bs - Wn - 1];
        R.t  = *(const int2*)(tg + bs);
        R.u0 = *(const int2*)(ct + 0 * HW + bs);
        R.u1 = *(const int2*)(ct + 1 * HW + bs);
        R.u2 = *(const int2*)(ct + 2 * HW + bs);
        R.u3 = *(const int2*)(ct + 3 * HW + bs);
        R.u4 = *(const int2*)(ct + 4 * HW + bs);
        R.u5 = *(const int2*)(ct + 5 * HW + bs);
        R.u6 = *(const int2*)(ct + 6 * HW + bs);
        R.u7 = *(const int2*)(ct + 7 * HW + bs);
    };

    // ---- kick off row hstart loads FIRST (fly under prologue sigmas) ----
    Row cu, nx;
    issue(hstart, cu);

    // ---- carried window: sigma(ch0..2)@h, sigma(ch5..7)@h-1 ----
    float C0[2], C1[2], C2[2], P5[2], P6[2], P7[2];
    {
        const int pb = hstart * Wn + wq;
        sig2(*(const float2*)(cm + 0 * HW + pb), C0);
        sig2(*(const float2*)(cm + 1 * HW + pb), C1);
        sig2(*(const float2*)(cm + 2 * HW + pb), C2);
    }
    if (hstart > 0) {   // block-uniform
        const int pb = (hstart - 1) * Wn + wq;
        sig2(*(const float2*)(cm + 5 * HW + pb), P5);
        sig2(*(const float2*)(cm + 6 * HW + pb), P6);
        sig2(*(const float2*)(cm + 7 * HW + pb), P7);
    } else {
#pragma unroll
        for (int k = 0; k < 2; ++k) { P5[k] = 0.f; P6[k] = 0.f; P7[k] = 0.f; }
    }

    const bool edR = (wq + 2 == Wn);
    const bool edL = (wq == 0);

#pragma unroll
    for (int r = 0; r < WALK; ++r) {
        const int  h     = hstart + r;
        const int  base  = h * Wn + wq;
        const bool hasDn = (h + 1 < Hn);
        const bool hasUp = (h > 0);

        // ---- prefetch next row before touching cu (compile-time guard) ----
        if (r + 1 < WALK) issue(h + 1, nx);
        (void)base;

        // ---- con bits ----
        unsigned lo = 0u;
        auto mix = [&](const int2& u, int c) {
            lo |= ((unsigned)u.x << c) | ((unsigned)u.y << (8 + c));
        };
        mix(cu.u0, 0); mix(cu.u1, 1); mix(cu.u2, 2); mix(cu.u3, 3);
        mix(cu.u4, 4); mix(cu.u5, 5); mix(cu.u6, 6); mix(cu.u7, 7);

        // ---- fresh centers ch3-7: sigma + conmap d-product accumulation ----
        float dp[2] = {1.f, 1.f};   // prod of d over ch3..7
        float ys[2] = {0.f, 0.f};   // sum of y where bit==0
        float c3[2], c4[2], c5[2], c6[2], c7[2];
        auto fresh = [&](int c, const float2& v, float s[2]) {
            const float xs[2] = {v.x, v.y};
#pragma unroll
            for (int k = 0; k < 2; ++k) {
                const float y = xs[k] * L2E;
                const float e = fexp2(-y);
                const float d = 1.f + e;
                s[k] = frcp(d);
                dp[k] *= d;
                ys[k] += ((lo >> (8 * k + c)) & 1u) ? 0.f : y;
            }
        };
        fresh(3, cu.a3, c3); fresh(4, cu.a4, c4); fresh(5, cu.a5, c5);
        fresh(6, cu.a6, c6); fresh(7, cu.a7, c7);

        // ---- conmap: carried ch0-2 select-product + ch3-7 d-form ----
#pragma unroll
        for (int k = 0; k < 2; ++k) {
            const float q0 = ((lo >> (8 * k + 0)) & 1u) ? C0[k] : 1.f - C0[k];
            const float q1 = ((lo >> (8 * k + 1)) & 1u) ? C1[k] : 1.f - C1[k];
            const float q2 = ((lo >> (8 * k + 2)) & 1u) ? C2[k] : 1.f - C2[k];
            s_con += flog2(q0 * q1 * q2) - flog2(dp[k]) - ys[k];
        }

        // ---- next-row sigmas + boundary sigmas ----
        float F0[2], F1[2], F2[2];
        sig2(cu.f0, F0); sig2(cu.f1, F1); sig2(cu.f2, F2);
        const float s0b = frcp(1.f + fexp2(-cu.b0 * L2E));
        const float s2b = frcp(1.f + fexp2(-cu.b2 * L2E));
        const float s3b = frcp(1.f + fexp2(-cu.b3 * L2E));
        const float s4b = frcp(1.f + fexp2(-cu.b4 * L2E));
        const float s5b = frcp(1.f + fexp2(-cu.b5 * L2E));
        const float s7b = frcp(1.f + fexp2(-cu.b7 * L2E));

        // ---- neighbor arrays n[c] (masked shifts) ----
        float n0[2], n1[2], n2[2], n3[2], n4[2], n5[2], n6[2], n7[2];
        n0[0] = F0[1]; n3[0] = c3[1]; n5[0] = P5[1];
        n2[1] = F2[0]; n4[1] = c4[0]; n7[1] = P7[0];
        n0[1] = edR ? 0.f : s0b;  n3[1] = edR ? 0.f : s3b;  n5[1] = edR ? 0.f : s5b;
        n2[0] = edL ? 0.f : s2b;  n4[0] = edL ? 0.f : s4b;  n7[0] = edL ? 0.f : s7b;
#pragma unroll
        for (int k = 0; k < 2; ++k) {
            n1[k] = hasDn ? F1[k] : 0.f;
            n6[k] = hasUp ? P6[k] : 0.f;
            if (!hasDn) { n0[k] = 0.f; n2[k] = 0.f; }
            if (!hasUp) { n5[k] = 0.f; n7[k] = 0.f; }
        }

        // ---- votes + bimap product accumulation ----
        float vmax[2] = {0.f, 0.f}, vmin[2] = {2.f, 2.f};
        float pr[2]   = {1.f, 1.f};
        float zc[2]   = {0.f, 0.f};   // count of bit=1 zero-votes
        auto vote = [&](int i, const float p[2], const float n[2]) {
#pragma unroll
            for (int k = 0; k < 2; ++k) {
                const float v = p[k] * n[k];
                vmax[k] = fmaxf(vmax[k], v);
                vmin[k] = fminf(vmin[k], v);
                const bool bit = (lo >> (8 * k + i)) & 1u;
                const bool z   = bit && (v == 0.f);     // only from masked edges
                float sel = bit ? v : 1.f - v;
                sel = z ? 1.f : sel;
                zc[k] += z ? 1.f : 0.f;
                pr[k] *= sel;
            }
        };
        vote(0, C0, n7); vote(1, C1, n6); vote(2, C2, n5); vote(3, c3, n4);
#pragma unroll
        for (int k = 0; k < 2; ++k) { s_bi += flog2(pr[k]); pr[k] = 1.f; }
        vote(4, c4, n3); vote(5, c5, n2); vote(6, c6, n1); vote(7, c7, n0);
#pragma unroll
        for (int k = 0; k < 2; ++k) { s_bi += flog2(pr[k]) + CLMP * zc[k]; }

        // ---- per-pixel tail ----
        const int tk[2] = {cu.t.x, cu.t.y};
#pragma unroll
        for (int k = 0; k < 2; ++k) {
            const float fm = vmax[k];
            s_bce += fmaxf(flog2(tk[k] ? fm : 1.f - fm), CLMP);
            const int sc = __popc((int)((lo >> (8 * k)) & 0xffu));
            s_dec += (sc > 0 && sc < 8) ? fmaxf(flog2(1.f - vmin[k]), CLMP) : 0.f;
            ci[k] += (float)tk[k];
            cj[k] += fm;
            cx[k] += tk[k] ? fm : 0.f;
        }

        // ---- rotate window + pipeline ----
#pragma unroll
        for (int k = 0; k < 2; ++k) {
            C0[k] = F0[k]; C1[k] = F1[k]; C2[k] = F2[k];
            P5[k] = c5[k]; P6[k] = c6[k]; P7[k] = c7[k];
        }
        if (r + 1 < WALK) cu = nx;   // waits for nx here == start of next iter
    }

    // ---- dice partials: thread-exclusive columns, direct store ----
    if constexpr (SLAB) {
        const size_t sb = ((size_t)work) << 9;
        float2 vi; vi.x = ci[0]; vi.y = ci[1];
        float2 vj; vj.x = cj[0]; vj.y = cj[1];
        float2 vx; vx.x = cx[0]; vx.y = cx[1];
        *(float2*)(col_i + sb + wq) = vi;
        *(float2*)(col_j + sb + wq) = vj;
        *(float2*)(col_x + sb + wq) = vx;
    } else {
#pragma unroll
        for (int k = 0; k < 2; ++k) {
            atomicAdd(&col_i[b * Wn + wq + k], ci[k]);
            atomicAdd(&col_j[b * Wn + wq + k], cj[k]);
            atomicAdd(&col_x[b * Wn + wq + k], cx[k]);
        }
    }

    // ---- scalar sums: wave shuffle reduction ----
#pragma unroll
    for (int off = 32; off > 0; off >>= 1) {
        s_con += __shfl_down(s_con, off);
        s_bi  += __shfl_down(s_bi,  off);
        s_bce += __shfl_down(s_bce, off);
        s_dec += __shfl_down(s_dec, off);
    }
    __shared__ float wred[4][4];
    if (lane == 0) {   // convert log2 -> ln units here (one mul per sum)
        wred[wv][0] = s_con * LN2; wred[wv][1] = s_bi * LN2;
        wred[wv][2] = s_bce * LN2; wred[wv][3] = s_dec * LN2;
    }
    __syncthreads();
    if (tid < 4) {
        bscal[(size_t)work * 4 + tid] =
            (double)(wred[0][tid] + wred[1][tid] + wred[2][tid] + wred[3][tid]);
    }
}

// Slab finisher: 256 blocks x 256 threads. Block bx owns 32 columns; each
// column's 128 gx-partials are summed by 8 threads (16 each) -> LDS -> lane.
__global__ __launch_bounds__(256) void bicon_finish_slab(
    const float* __restrict__ pI,
    const float* __restrict__ pJ,
    const float* __restrict__ pX,
    const double* __restrict__ bscal,
    float* __restrict__ out)
{
    const int tid = threadIdx.x;
    const int w32 = tid & 31;                 // which of the block's 32 columns
    const int p   = tid >> 5;                 // gx partition 0..7 (16 gx each)
    const int col = blockIdx.x * 32 + w32;    // 0..8191
    const int b   = col >> 9;
    const int w   = col & 511;

    float fi = 0.f, fj = 0.f, fx = 0.f;
    const size_t base = (((size_t)(b * GX + p * 16)) << 9) + w;
#pragma unroll
    for (int g = 0; g < 16; ++g) {
        const size_t idx = base + ((size_t)g << 9);
        fi += pI[idx]; fj += pJ[idx]; fx += pX[idx];
    }
    __shared__ float red[3][8][32];           // 3 KB
    red[0][p][w32] = fi; red[1][p][w32] = fj; red[2][p][w32] = fx;
    __syncthreads();

    double part = 0.0;
    if (tid < 32) {                           // dice term for 32 columns
        float si = 0.f, sj = 0.f, sx = 0.f;
#pragma unroll
        for (int q = 0; q < 8; ++q) {
            si += red[0][q][tid]; sj += red[1][q][tid]; sx += red[2][q][tid];
        }
        part = (1.0 - (2.0 * (double)sx + 0.001) /
                      ((double)si + (double)sj + 0.001)) / 8192.0;
    }
    if (tid >= 64 && tid < 72) {              // 8 bscal slots, on wave 1
        const int s = blockIdx.x * 8 + (tid - 64);
        const double c0 = bscal[s * 4 + 0], c1 = bscal[s * 4 + 1];
        const double c2 = bscal[s * 4 + 2], c3 = bscal[s * 4 + 3];
        part += -0.8 * c0 / 33554432.0 - 0.2 * c1 / 33554432.0
                - c2 / 4194304.0 - c3 / 4194304.0;
    }
#pragma unroll
    for (int off = 32; off > 0; off >>= 1) part += __shfl_down(part, off);
    __shared__ double red2[4];
    if ((tid & 63) == 0) red2[tid >> 6] = part;
    __syncthreads();
    if (tid == 0) atomicAdd(out, (float)(red2[0] + red2[1] + red2[2] + red2[3]));
}

// Fallback finisher (atomic path): cols already reduced, 32 blocks suffice.
__global__ __launch_bounds__(256) void bicon_finish(
    const float* __restrict__ col_i,
    const float* __restrict__ col_j,
    const float* __restrict__ col_x,
    const double* __restrict__ bscal,
    float* __restrict__ out)
{
    const int tid = threadIdx.x;
    const int col = blockIdx.x * 256 + tid;      // exactly NCOL threads total

    double part;
    {
        const float fi = col_i[col], fj = col_j[col], fx = col_x[col];
        part = (1.0 - (2.0 * (double)fx + 0.001) /
                      ((double)fi + (double)fj + 0.001)) / 8192.0;
    }
    if (tid < 64) {   // 64 bscal slots per block: 32 blocks * 64 = 2048 = NBLK
        const int s = blockIdx.x * 64 + tid;
        const double c0 = bscal[s * 4 + 0], c1 = bscal[s * 4 + 1];
        const double c2 = bscal[s * 4 + 2], c3 = bscal[s * 4 + 3];
        part += -0.8 * c0 / 33554432.0 - 0.2 * c1 / 33554432.0
                - c2 / 4194304.0 - c3 / 4194304.0;
    }
#pragma unroll
    for (int off = 32; off > 0; off >>= 1) part += __shfl_down(part, off);
    __shared__ double red[4];
    if ((tid & 63) == 0) red[tid >> 6] = part;
    __syncthreads();
    if (tid == 0) atomicAdd(out, (float)(red[0] + red[1] + red[2] + red[3]));
}

extern "C" void kernel_launch(void* const* d_in, const int* in_sizes, int n_in,
                              void* d_out, int out_size, void* d_ws, size_t ws_size,
                              hipStream_t stream) {
    const float* c_map      = (const float*)d_in[0];
    const int*   target     = (const int*)d_in[1];
    const int*   con_target = (const int*)d_in[2];
    float* out = (float*)d_out;

    char* ws = (char*)d_ws;
    const size_t slab_need = (size_t)3 * SLABN * sizeof(float)
                           + (size_t)NBLK * 4 * sizeof(double);   // ~12.65 MB

    dim3 grid(GX, Bn);       // 128 x 16 = 2048 blocks
    dim3 block(256);

    hipMemsetAsync(d_out, 0, sizeof(float), stream);  // finisher atomics here

    if (ws_size >= slab_need) {
        float*  pI    = (float*)ws;                   // 2048 x 512 partials
        float*  pJ    = pI + SLABN;
        float*  pX    = pJ + SLABN;
        double* bscal = (double*)(ws + (size_t)3 * SLABN * sizeof(float));
        // no col memset needed: slabs are fully written
        bicon_main<true><<<grid, block, 0, stream>>>(c_map, target, con_target,
                                                     pI, pJ, pX, bscal);
        bicon_finish_slab<<<FBLK2, 256, 0, stream>>>(pI, pJ, pX, bscal, out);
    } else {
        float*  col_i = (float*)ws;                               // 8192 floats
        float*  col_j = col_i + NCOL;
        float*  col_x = col_j + NCOL;
        double* bscal = (double*)(ws + 3 * NCOL * sizeof(float)); // 2048*4 doubles
        hipMemsetAsync(d_ws, 0, 3 * NCOL * sizeof(float), stream);
        bicon_main<false><<<grid, block, 0, stream>>>(c_map, target, con_target,
                                                      col_i, col_j, col_x, bscal);
        bicon_finish<<<FBLK, 256, 0, stream>>>(col_i, col_j, col_x, bscal, out);
    }
}